// Round 3
// baseline (372.752 us; speedup 1.0000x reference)
//
#include <hip/hip_runtime.h>

#ifndef __has_builtin
#define __has_builtin(x) 0
#endif

#define NOBS_OS 8
#define NOBS_TS 6
#define HID 128
#define NACT 9
#define BTOT 32768
#define NTS 32
#define ROWS 16        // batch rows per tile
#define NTILES 2048    // 2048*16 = 32768
#define PAIRS 1024     // one block per pair of adjacent sorted tiles
#define BLOCK 1024     // 16 waves; 2 groups of 8; group g owns chain g
#define PREB 128       // pre-pass blocks (256 thr each)

// workspace layout (int32 offsets)
#define LEN_OFF 0
#define PERM_OFF BTOT
#define HIST_OFF (2 * BTOT)   // PREB x 33 per-block histograms

typedef __attribute__((ext_vector_type(8))) short short8;
typedef __attribute__((ext_vector_type(4))) float f32x4;

__device__ inline unsigned short f2bf(float x) {
  unsigned int u = __float_as_uint(x);
  u += 0x7FFFu + ((u >> 16) & 1u);
  return (unsigned short)(u >> 16);
}

// packed f32x2 -> bf16x2 (low = a, high = b)
__device__ inline unsigned pkbf(float a, float b) {
#if __has_builtin(__builtin_amdgcn_cvt_pk_bf16_f32)
  auto v = __builtin_amdgcn_cvt_pk_bf16_f32(a, b);
  unsigned u;
  __builtin_memcpy(&u, &v, sizeof(u));
  return u;
#else
  return ((unsigned)f2bf(b) << 16) | (unsigned)f2bf(a);
#endif
}

__device__ inline float fexp2(float x) {
#if __has_builtin(__builtin_amdgcn_exp2f)
  return __builtin_amdgcn_exp2f(x);
#else
  return exp2f(x);
#endif
}
__device__ inline float frcp_(float x) {
#if __has_builtin(__builtin_amdgcn_rcpf)
  return __builtin_amdgcn_rcpf(x);
#else
  return 1.0f / x;
#endif
}

__device__ inline short8 pack8(f32x4 a, f32x4 b) {
  union { unsigned u[4]; short8 s; } r;
  r.u[0] = pkbf(a[0], a[1]); r.u[1] = pkbf(a[2], a[3]);
  r.u[2] = pkbf(b[0], b[1]); r.u[3] = pkbf(b[2], b[3]);
  return r.s;
}

__device__ inline short8 pack8s(const float* p, float s) {
  union { unsigned u[4]; short8 r; } r;
#pragma unroll
  for (int i = 0; i < 4; ++i) r.u[i] = pkbf(p[2 * i] * s, p[2 * i + 1] * s);
  return r.r;
}

// ---- fused counting-sort pre-pass (2 kernels, no global atomics) --------
__global__ void count_kernel(const float* __restrict__ s, int* __restrict__ ws) {
  __shared__ int lh[NTS + 1];
  const int tid = threadIdx.x;
  if (tid <= NTS) lh[tid] = 0;
  __syncthreads();
  const int row = blockIdx.x * 256 + tid;
  const float* p = s + (size_t)row * 200 + NOBS_OS;
  int lo = 0, hi = NTS;
  while (lo < hi) {
    const int mid = (lo + hi) >> 1;
    const float v = p[mid * NOBS_TS];
    if (v == v) lo = mid + 1; else hi = mid;
  }
  ws[LEN_OFF + row] = lo;
  atomicAdd(&lh[lo], 1);
  __syncthreads();
  if (tid <= NTS) ws[HIST_OFF + blockIdx.x * (NTS + 1) + tid] = lh[tid];
}

__global__ void scatter_kernel(int* __restrict__ ws) {
  __shared__ int tot[NTS + 1], pre[NTS + 1], gb[NTS + 1], lh[NTS + 1];
  const int tid = threadIdx.x;
  if (tid <= NTS) {
    int t = 0, pr = 0;
    for (int k = 0; k < PREB; ++k) {
      const int h = ws[HIST_OFF + k * (NTS + 1) + tid];
      t += h;
      if (k < (int)blockIdx.x) pr += h;
    }
    tot[tid] = t;
    pre[tid] = pr;
    lh[tid] = 0;
  }
  __syncthreads();
  if (tid == 0) {
    int a = 0;
    for (int b = 0; b <= NTS; ++b) { gb[b] = a; a += tot[b]; }
  }
  __syncthreads();
  const int row = blockIdx.x * 256 + tid;
  const int len = ws[LEN_OFF + row];
  const int r = atomicAdd(&lh[len], 1);
  __syncthreads();
  ws[PERM_OFF + gb[len] + pre[len] + r] = row;
}

// ---- main fused kernel: 16 waves, 2 groups of 8, chain-per-group --------
// Block = 1024 thr = 16 waves = exactly 4 waves/SIMD at 1 block/CU (occ 50%
// by construction; round-2 showed 2 co-resident 8-wave blocks is VGPR-
// unreachable). Group g (waves 8g..8g+7) owns chain g entirely: its hA[g]
// buffer is produced and consumed only by its own 8 waves, so the two
// groups are independent between block-wide barriers -> each SIMD holds 4
// independent instruction streams (2 per group) that hide each other's
// ds_read / MFMA-chain / transcendental latency.
// Register diet (forced 128-cap from 1024-thr block-fit; round-1 showed
// spills here are catastrophic):
//   - W_ih fragments live in LDS (wihf), re-read per GX (4 ds_read_b128);
//     gate bias folded in as input channel 6: x_st ch6 = 1.0, wihf ch6 =
//     scaled bias, MFMA C = reusable zero vector. Kills Bh[a][4] + biasv.
//   - x_TS capture writes straight to LDS (xtsb pre-zeroed); no xts regs.
// Loop-live ~ Bh[4][4](64) + acc[4](16) + cc(4) + misc ~ 109 regs.
// Weights prescaled: i,f,o by -1/log2(e), g by -2/log2(e); fused products:
//   i*g = (1-eg)*rcp((1+ei)(1+eg)); f*c = c*rcp(1+ef);
//   o*tanh(c) = (1-ec)*rcp((1+eo)(1+ec)), ec = exp2(-2c*log2e)
// A-frag layout in LDS (16 rows x K): elem idx = kt*512 + lane*8 + jj
// C-layout writes at column k: idx = (k>>5)*512 + ((k>>3)&3)*128 + m*8 + (k&7)
// Rows past their length get garbage h (bias-free now) -- harmless: matmul
// rows are independent and capture already happened at t = len-1.

#define GX(T)                                                                \
  {                                                                          \
    short8 ax = z8;                                                          \
    if (q == 0) ax = *(const short8*)&xstg[c * 264 + (T) * 8];               \
    _Pragma("unroll") for (int a = 0; a < 4; ++a) {                          \
      const short8 wf = *(const short8*)&wihf[(a * 128 + j) * 8];            \
      acc[a] = __builtin_amdgcn_mfma_f32_16x16x32_bf16(ax, wf, z4, 0, 0, 0); \
    }                                                                        \
  }

#define GH(T)                                                                \
  {                                                                          \
    const unsigned short* hb = hAg + ((((T) + 1) & 1) << 11);                \
    _Pragma("unroll") for (int kt = 0; kt < 4; ++kt) {                       \
      const short8 ah = *(const short8*)&hb[kt * 512 + L * 8];               \
      _Pragma("unroll") for (int a = 0; a < 4; ++a)                          \
          acc[a] = __builtin_amdgcn_mfma_f32_16x16x32_bf16(                  \
              ah, Bh[a][kt], acc[a], 0, 0, 0);                               \
    }                                                                        \
  }

#define ACT(T)                                                               \
  {                                                                          \
    unsigned short* hw = hAg + (((T) & 1) << 11) + pbase;                    \
    float hv[4];                                                             \
    _Pragma("unroll") for (int r = 0; r < 4; ++r) {                          \
      const float ei = fexp2(acc[0][r]);                                     \
      const float ef = fexp2(acc[1][r]);                                     \
      const float eg = fexp2(acc[2][r]);                                     \
      const float eo = fexp2(acc[3][r]);                                     \
      const float rig = frcp_((1.0f + ei) * (1.0f + eg));                    \
      const float rf = frcp_(1.0f + ef);                                     \
      const float cv = cc[r] * rf + (1.0f - eg) * rig;                       \
      cc[r] = cv;                                                            \
      const float ec = fexp2(cv * -2.88539008f);                             \
      const float roc = frcp_((1.0f + eo) * (1.0f + ec));                    \
      hv[r] = (1.0f - ec) * roc;                                             \
    }                                                                        \
    const unsigned p01 = pkbf(hv[0], hv[1]);                                 \
    const unsigned p23 = pkbf(hv[2], hv[3]);                                 \
    const unsigned short hb16_0 = (unsigned short)p01;                       \
    const unsigned short hb16_1 = (unsigned short)(p01 >> 16);               \
    const unsigned short hb16_2 = (unsigned short)p23;                       \
    const unsigned short hb16_3 = (unsigned short)(p23 >> 16);               \
    hw[0] = hb16_0;                                                          \
    hw[8] = hb16_1;                                                          \
    hw[16] = hb16_2;                                                         \
    hw[24] = hb16_3;                                                         \
    if (((tpck >> 0) & 255u) == (unsigned)(T)) xtsbg[pbase + 0] = hb16_0;    \
    if (((tpck >> 8) & 255u) == (unsigned)(T)) xtsbg[pbase + 8] = hb16_1;    \
    if (((tpck >> 16) & 255u) == (unsigned)(T)) xtsbg[pbase + 16] = hb16_2;  \
    if (((tpck >> 24) & 255u) == (unsigned)(T)) xtsbg[pbase + 24] = hb16_3;  \
  }

__global__ __launch_bounds__(BLOCK) void recdqn_kernel(
    const float* __restrict__ s, const float* __restrict__ W_os,
    const float* __restrict__ b_os, const float* __restrict__ W_ih,
    const float* __restrict__ W_hh, const float* __restrict__ b_ih,
    const float* __restrict__ b_hh, const float* __restrict__ W_ts,
    const float* __restrict__ b_ts, const float* __restrict__ W_c1,
    const float* __restrict__ b_c1, const float* __restrict__ W_c2,
    const float* __restrict__ b_c2, const int* __restrict__ ws,
    float* __restrict__ out) {
  __shared__ unsigned short x_st[2][ROWS * 264]; // [chain][row][t][8] bf16
  __shared__ unsigned short hA[2][2][2048];      // [chain][buf] h A-frag
  __shared__ unsigned short xtsb[2][2048];       // captured h at t=len-1
  __shared__ unsigned short wihf[4 * 128 * 8];   // W_ih frags, ch6 = bias
  __shared__ unsigned short xcat[2][4096];       // concat A-frag, per group
  __shared__ unsigned short x2b[2][2048];        // W_c1 out A-frag, per group
  __shared__ int n_lds[2][ROWS];
  __shared__ int rid_s[2][ROWS];
  __shared__ int tmax_sh[2];

  const int tid = threadIdx.x;
  const int L = tid & 63;
  const int w = tid >> 6;   // wave 0..15
  const int g = w >> 3;     // group = chain 0..1
  const int ww = w & 7;     // wave within group: hidden cols [16ww,16ww+16)
  const int c = L & 15;
  const int q = L >> 4;
  const int j = (ww << 4) | c;

  const short8 z8 = {0, 0, 0, 0, 0, 0, 0, 0};
  const f32x4 z4 = {0.0f, 0.0f, 0.0f, 0.0f};

  // ---- one-time: prescaled W_hh B-fragments (regs; W_ih+bias go to LDS)
  short8 Bh[4][4];
#pragma unroll
  for (int a = 0; a < 4; ++a) {
    const float sc = (a == 2) ? -2.88539008f : -1.44269504f;
    const int n = (a << 7) + j;
#pragma unroll
    for (int kt = 0; kt < 4; ++kt)
      Bh[a][kt] = pack8s(W_hh + n * HID + kt * 32 + q * 8, sc);
  }

  const int pbase = ((j >> 5) << 9) + (((j >> 3) & 3) << 7) + (q << 5) + (j & 7);

  // ---- pick tile pair: adjacent sorted tiles, longest-first (LPT)
  const int p = (PAIRS - 1) - blockIdx.x;
  if (tid < 32) {
    const int cn = tid >> 4, rr = tid & 15;
    const int row = ws[PERM_OFF + (2 * p + cn) * ROWS + rr];
    rid_s[cn][rr] = row;
    n_lds[cn][rr] = ws[LEN_OFF + row];
  }
  // ---- wihf staging (W_ih prescaled + bias in channel 6) + xtsb zero
  if (tid < 512) {
    const int a = tid >> 7, jj = tid & 127, n = (a << 7) + jj;
    const float sc = (a == 2) ? -2.88539008f : -1.44269504f;
    const float* px = W_ih + n * NOBS_TS;
    union { unsigned u[4]; short8 s; } fu;
    fu.u[0] = pkbf(px[0] * sc, px[1] * sc);
    fu.u[1] = pkbf(px[2] * sc, px[3] * sc);
    fu.u[2] = pkbf(px[4] * sc, px[5] * sc);
    fu.u[3] = pkbf(sc * (b_ih[n] + b_hh[n]), 0.0f);
    *(short8*)&wihf[tid * 8] = fu.s;
    *(short8*)&((unsigned short*)xtsb)[tid * 8] = z8;
  }
  __syncthreads();

  // ---- stage s_TS -> LDS bf16 for both chains (ch6 = 1.0 inside length)
  {
    const int cn = tid >> 9, rt = tid & 511, r = rt >> 5, tq = rt & 31;
    short8 v = z8;
    if (tq < n_lds[cn][r]) {
      const float2* ps =
          (const float2*)(s + (size_t)rid_s[cn][r] * 200 + NOBS_OS + tq * NOBS_TS);
      const float2 A = ps[0], Bv = ps[1], Cv = ps[2];
      union { unsigned u[4]; short8 s; } vu;
      vu.u[0] = pkbf(A.x, A.y);
      vu.u[1] = pkbf(Bv.x, Bv.y);
      vu.u[2] = pkbf(Cv.x, Cv.y);
      vu.u[3] = pkbf(1.0f, 0.0f);   // bias channel
      v = vu.s;
    }
    *(short8*)&x_st[cn][r * 264 + tq * 8] = v;
  }
  if (tid == 0) {
#pragma unroll
    for (int cn = 0; cn < 2; ++cn) {
      int mx = 0;
      for (int r = 0; r < ROWS; ++r) mx = max(mx, n_lds[cn][r]);
      tmax_sh[cn] = mx;
    }
  }
  __syncthreads();

  const int tm1 = tmax_sh[1];           // chains sorted ascending: tm0 <= tm1
  const int tmg = tmax_sh[g];           // my group's trip count
  unsigned tpck = 0;
#pragma unroll
  for (int b = 0; b < 4; ++b)
    tpck |= ((unsigned)((n_lds[g][q * 4 + b] - 1) & 255)) << (b * 8);

  float cc[4] = {0.0f, 0.0f, 0.0f, 0.0f};
  const unsigned short* xstg = &x_st[g][0];
  unsigned short* hAg = &hA[g][0][0];
  unsigned short* xtsbg = &xtsb[g][0];

  // ---- LSTM time loop: group-predicated work, block-wide barriers
  f32x4 acc[4];
  if (tm1 > 0) {
    if (tmg > 0) { GX(0) ACT(0) }
    __syncthreads();
    for (int t = 1; t < tm1; ++t) {
      if (t < tmg) { GX(t) GH(t) ACT(t) }
      __syncthreads();
    }
  }

  // ---- hoisted head weight fragments (bf16); Bh dead by now
  short8 Fts[4], Fc1[8], Fc2[4], bosf = z8;
#pragma unroll
  for (int kt = 0; kt < 4; ++kt) {
    const f32x4* pp = (const f32x4*)(W_ts + j * HID + kt * 32 + q * 8);
    Fts[kt] = pack8(pp[0], pp[1]);
  }
#pragma unroll
  for (int kt = 0; kt < 8; ++kt) {
    const f32x4* pp = (const f32x4*)(W_c1 + j * 256 + kt * 32 + q * 8);
    Fc1[kt] = pack8(pp[0], pp[1]);
  }
#pragma unroll
  for (int kt = 0; kt < 4; ++kt) Fc2[kt] = z8;
  if (ww == 0 && c < NACT) {
#pragma unroll
    for (int kt = 0; kt < 4; ++kt) {
      const f32x4* pp = (const f32x4*)(W_c2 + c * HID + kt * 32 + q * 8);
      Fc2[kt] = pack8(pp[0], pp[1]);
    }
  }
  if (q == 0) {
    const f32x4* pb = (const f32x4*)(W_os + j * NOBS_OS);
    bosf = pack8(pb[0], pb[1]);
  }
  const float bts = b_ts[j], bc1 = b_c1[j], bos = b_os[j];
  const float bc2 = (ww == 0 && c < NACT) ? b_c2[c] : 0.0f;

  // ---- heads: each group processes its own chain concurrently
  // x_TS = relu(xts @ W_ts^T + b_ts) -> xcat[g] k=128+j
  {
    f32x4 a2 = {bts, bts, bts, bts};
#pragma unroll
    for (int kt = 0; kt < 4; ++kt) {
      const short8 af = *(const short8*)&xtsbg[kt * 512 + L * 8];
      a2 = __builtin_amdgcn_mfma_f32_16x16x32_bf16(af, Fts[kt], a2, 0, 0, 0);
    }
    const unsigned p01 = pkbf(fmaxf(a2[0], 0.0f), fmaxf(a2[1], 0.0f));
    const unsigned p23 = pkbf(fmaxf(a2[2], 0.0f), fmaxf(a2[3], 0.0f));
    xcat[g][2048 + pbase + 0] = (unsigned short)p01;
    xcat[g][2048 + pbase + 8] = (unsigned short)(p01 >> 16);
    xcat[g][2048 + pbase + 16] = (unsigned short)p23;
    xcat[g][2048 + pbase + 24] = (unsigned short)(p23 >> 16);
  }
  // x_OS = relu(s_OS @ W_os^T + b_os) -> xcat[g] k=j
  {
    short8 aos = z8;
    if (q == 0) {
      const f32x4* pa = (const f32x4*)(s + (size_t)rid_s[g][c] * 200);
      aos = pack8(pa[0], pa[1]);
    }
    f32x4 a2 = {bos, bos, bos, bos};
    a2 = __builtin_amdgcn_mfma_f32_16x16x32_bf16(aos, bosf, a2, 0, 0, 0);
    const unsigned p01 = pkbf(fmaxf(a2[0], 0.0f), fmaxf(a2[1], 0.0f));
    const unsigned p23 = pkbf(fmaxf(a2[2], 0.0f), fmaxf(a2[3], 0.0f));
    xcat[g][pbase + 0] = (unsigned short)p01;
    xcat[g][pbase + 8] = (unsigned short)(p01 >> 16);
    xcat[g][pbase + 16] = (unsigned short)p23;
    xcat[g][pbase + 24] = (unsigned short)(p23 >> 16);
  }
  __syncthreads();
  // x = relu(xcat @ W_c1^T + b_c1) -> x2b[g] (K=256)
  {
    f32x4 a2 = {bc1, bc1, bc1, bc1};
#pragma unroll
    for (int kt = 0; kt < 8; ++kt) {
      const short8 af = *(const short8*)&xcat[g][kt * 512 + L * 8];
      a2 = __builtin_amdgcn_mfma_f32_16x16x32_bf16(af, Fc1[kt], a2, 0, 0, 0);
    }
    const unsigned p01 = pkbf(fmaxf(a2[0], 0.0f), fmaxf(a2[1], 0.0f));
    const unsigned p23 = pkbf(fmaxf(a2[2], 0.0f), fmaxf(a2[3], 0.0f));
    x2b[g][pbase + 0] = (unsigned short)p01;
    x2b[g][pbase + 8] = (unsigned short)(p01 >> 16);
    x2b[g][pbase + 16] = (unsigned short)p23;
    x2b[g][pbase + 24] = (unsigned short)(p23 >> 16);
  }
  __syncthreads();
  // out = x2 @ W_c2^T + b_c2 (wave ww==0 of each group; cols c<9 valid)
  if (ww == 0) {
    f32x4 accf = {bc2, bc2, bc2, bc2};
#pragma unroll
    for (int kt = 0; kt < 4; ++kt) {
      const short8 af = *(const short8*)&x2b[g][kt * 512 + L * 8];
      accf = __builtin_amdgcn_mfma_f32_16x16x32_bf16(af, Fc2[kt], accf, 0, 0, 0);
    }
    if (c < NACT) {
#pragma unroll
      for (int r = 0; r < 4; ++r)
        out[(size_t)rid_s[g][q * 4 + r] * NACT + c] = accf[r];
    }
  }
}

extern "C" void kernel_launch(void* const* d_in, const int* in_sizes, int n_in,
                              void* d_out, int out_size, void* d_ws, size_t ws_size,
                              hipStream_t stream) {
  (void)in_sizes; (void)n_in; (void)out_size; (void)ws_size;
  const float* s    = (const float*)d_in[0];
  const float* W_os = (const float*)d_in[1];
  const float* b_os = (const float*)d_in[2];
  const float* W_ih = (const float*)d_in[3];
  const float* W_hh = (const float*)d_in[4];
  const float* b_ih = (const float*)d_in[5];
  const float* b_hh = (const float*)d_in[6];
  const float* W_ts = (const float*)d_in[7];
  const float* b_ts = (const float*)d_in[8];
  const float* W_c1 = (const float*)d_in[9];
  const float* b_c1 = (const float*)d_in[10];
  const float* W_c2 = (const float*)d_in[11];
  const float* b_c2 = (const float*)d_in[12];
  int* ws = (int*)d_ws;
  float* outp = (float*)d_out;

  count_kernel<<<PREB, 256, 0, stream>>>(s, ws);
  scatter_kernel<<<PREB, 256, 0, stream>>>(ws);
  recdqn_kernel<<<PAIRS, BLOCK, 0, stream>>>(
      s, W_os, b_os, W_ih, W_hh, b_ih, b_hh, W_ts, b_ts, W_c1, b_c1, W_c2,
      b_c2, ws, outp);
}

// Round 5
// 309.386 us; speedup vs baseline: 1.2048x; 1.2048x over previous
//
#include <hip/hip_runtime.h>

#ifndef __has_builtin
#define __has_builtin(x) 0
#endif

#define NOBS_OS 8
#define NOBS_TS 6
#define HID 128
#define NACT 9
#define BTOT 32768
#define NTS 32
#define ROWS 16        // batch rows per tile
#define NTILES 2048    // 2048*16 = 32768
#define PAIRS 1024     // one block per pair of adjacent sorted tiles
#define BLOCK 1024     // 16 waves; 2 groups of 8; group g owns chain g
#define PREB 128       // pre-pass blocks (256 thr each)

// workspace layout (int32 offsets)
#define LEN_OFF 0
#define PERM_OFF BTOT
#define HIST_OFF (2 * BTOT)   // PREB x 33 per-block histograms

typedef __attribute__((ext_vector_type(8))) short short8;
typedef __attribute__((ext_vector_type(4))) float f32x4;

__device__ inline unsigned short f2bf(float x) {
  unsigned int u = __float_as_uint(x);
  u += 0x7FFFu + ((u >> 16) & 1u);
  return (unsigned short)(u >> 16);
}

// packed f32x2 -> bf16x2 (low = a, high = b)
__device__ inline unsigned pkbf(float a, float b) {
#if __has_builtin(__builtin_amdgcn_cvt_pk_bf16_f32)
  auto v = __builtin_amdgcn_cvt_pk_bf16_f32(a, b);
  unsigned u;
  __builtin_memcpy(&u, &v, sizeof(u));
  return u;
#else
  return ((unsigned)f2bf(b) << 16) | (unsigned)f2bf(a);
#endif
}

__device__ inline float fexp2(float x) {
#if __has_builtin(__builtin_amdgcn_exp2f)
  return __builtin_amdgcn_exp2f(x);
#else
  return exp2f(x);
#endif
}
__device__ inline float frcp_(float x) {
#if __has_builtin(__builtin_amdgcn_rcpf)
  return __builtin_amdgcn_rcpf(x);
#else
  return 1.0f / x;
#endif
}

__device__ inline short8 pack8(f32x4 a, f32x4 b) {
  union { unsigned u[4]; short8 s; } r;
  r.u[0] = pkbf(a[0], a[1]); r.u[1] = pkbf(a[2], a[3]);
  r.u[2] = pkbf(b[0], b[1]); r.u[3] = pkbf(b[2], b[3]);
  return r.s;
}

__device__ inline short8 pack8s(const float* p, float s) {
  union { unsigned u[4]; short8 r; } r;
#pragma unroll
  for (int i = 0; i < 4; ++i) r.u[i] = pkbf(p[2 * i] * s, p[2 * i + 1] * s);
  return r.r;
}

// ---- fused counting-sort pre-pass (2 kernels, no global atomics) --------
__global__ void count_kernel(const float* __restrict__ s, int* __restrict__ ws) {
  __shared__ int lh[NTS + 1];
  const int tid = threadIdx.x;
  if (tid <= NTS) lh[tid] = 0;
  __syncthreads();
  const int row = blockIdx.x * 256 + tid;
  const float* p = s + (size_t)row * 200 + NOBS_OS;
  int lo = 0, hi = NTS;
  while (lo < hi) {
    const int mid = (lo + hi) >> 1;
    const float v = p[mid * NOBS_TS];
    if (v == v) lo = mid + 1; else hi = mid;
  }
  ws[LEN_OFF + row] = lo;
  atomicAdd(&lh[lo], 1);
  __syncthreads();
  if (tid <= NTS) ws[HIST_OFF + blockIdx.x * (NTS + 1) + tid] = lh[tid];
}

__global__ void scatter_kernel(int* __restrict__ ws) {
  __shared__ int tot[NTS + 1], pre[NTS + 1], gb[NTS + 1], lh[NTS + 1];
  const int tid = threadIdx.x;
  if (tid <= NTS) {
    int t = 0, pr = 0;
    for (int k = 0; k < PREB; ++k) {
      const int h = ws[HIST_OFF + k * (NTS + 1) + tid];
      t += h;
      if (k < (int)blockIdx.x) pr += h;
    }
    tot[tid] = t;
    pre[tid] = pr;
    lh[tid] = 0;
  }
  __syncthreads();
  if (tid == 0) {
    int a = 0;
    for (int b = 0; b <= NTS; ++b) { gb[b] = a; a += tot[b]; }
  }
  __syncthreads();
  const int row = blockIdx.x * 256 + tid;
  const int len = ws[LEN_OFF + row];
  const int r = atomicAdd(&lh[len], 1);
  __syncthreads();
  ws[PERM_OFF + gb[len] + pre[len] + r] = row;
}

// ---- main fused kernel: 16 waves, 2 groups of 8, chain-per-group --------
// Round-3 structure (correct, occ 45%) + arch-register diet so the forced
// 128-unified cap (1024-thr block) doesn't spill (round-3: 310 MB scratch):
//   - HALF of W_hh (kt 2,3) lives in LDS (whh2, 64 KB, prescaled bf16,
//     shared by both groups); Bh regs shrink [4][4]->[4][2] (32 regs).
//     whh2 q-slot is XOR-swizzled by (j>>1)&3: un-swizzled, the 8 same-
//     parity lanes of each 16-lane group hit the same 4-bank window
//     (8-way conflict ~2.94x); swizzled -> 2 lanes/bank = free (m136).
//   - Heads are load-pack-use: no hoisted Fts/Fc1/Fc2/bosf arrays (round-3
//     kept ~68 regs live across the head phase -> spill).
//   - xcat/x2b alias whh2 (last whh2 read = final GH, before the loop's
//     final barrier; head writes after it). LDS total ~115 KB, 1 block/CU
//     (= design point: 16 waves = 4 waves/SIMD).
// Loop arch-live ~ Bh(32) + transients(12) + ACT temps(12) + control(10)
// ~ 66; acc[4] (16) can sit in the AGPR half. Total ~85 << 128.
// Weights prescaled: i,f,o by -1/log2(e), g by -2/log2(e); fused products:
//   i*g = (1-eg)*rcp((1+ei)(1+eg)); f*c = c*rcp(1+ef);
//   o*tanh(c) = (1-ec)*rcp((1+eo)(1+ec)), ec = exp2(-2c*log2e)
// A-frag layout in LDS (16 rows x K): elem idx = kt*512 + lane*8 + jj
// C-layout writes at column k: idx = (k>>5)*512 + ((k>>3)&3)*128 + m*8 + (k&7)
// Bias rides as input channel 6: x_st ch6 = 1.0, wihf ch6 = scaled bias.

#define GX(T)                                                                \
  {                                                                          \
    short8 ax = z8;                                                          \
    if (q == 0) ax = *(const short8*)&xstg[c * 264 + (T) * 8];               \
    _Pragma("unroll") for (int a = 0; a < 4; ++a) {                          \
      const short8 wf = *(const short8*)&wihf[(a * 128 + j) * 8];            \
      acc[a] = __builtin_amdgcn_mfma_f32_16x16x32_bf16(ax, wf, z4, 0, 0, 0); \
    }                                                                        \
  }

#define GH(T)                                                                \
  {                                                                          \
    const unsigned short* hb = hAg + ((((T) + 1) & 1) << 11);                \
    _Pragma("unroll") for (int kt = 0; kt < 2; ++kt) {                       \
      const short8 ah = *(const short8*)&hb[kt * 512 + L * 8];               \
      _Pragma("unroll") for (int a = 0; a < 4; ++a)                          \
          acc[a] = __builtin_amdgcn_mfma_f32_16x16x32_bf16(                  \
              ah, Bh[a][kt], acc[a], 0, 0, 0);                               \
    }                                                                        \
    _Pragma("unroll") for (int kt = 2; kt < 4; ++kt) {                       \
      const short8 ah = *(const short8*)&hb[kt * 512 + L * 8];               \
      _Pragma("unroll") for (int a = 0; a < 4; ++a) {                        \
        const short8 wf = *(const short8*)&whh2[                             \
            ((a * 2 + (kt - 2)) * 128 + j) * 32 + qsw];                      \
        acc[a] = __builtin_amdgcn_mfma_f32_16x16x32_bf16(                    \
            ah, wf, acc[a], 0, 0, 0);                                        \
      }                                                                      \
    }                                                                        \
  }

#define ACT(T)                                                               \
  {                                                                          \
    unsigned short* hw = hAg + (((T) & 1) << 11) + pbase;                    \
    float hv[4];                                                             \
    _Pragma("unroll") for (int r = 0; r < 4; ++r) {                          \
      const float ei = fexp2(acc[0][r]);                                     \
      const float ef = fexp2(acc[1][r]);                                     \
      const float eg = fexp2(acc[2][r]);                                     \
      const float eo = fexp2(acc[3][r]);                                     \
      const float rig = frcp_((1.0f + ei) * (1.0f + eg));                    \
      const float rf = frcp_(1.0f + ef);                                     \
      const float cv = cc[r] * rf + (1.0f - eg) * rig;                       \
      cc[r] = cv;                                                            \
      const float ec = fexp2(cv * -2.88539008f);                             \
      const float roc = frcp_((1.0f + eo) * (1.0f + ec));                    \
      hv[r] = (1.0f - ec) * roc;                                             \
    }                                                                        \
    const unsigned p01 = pkbf(hv[0], hv[1]);                                 \
    const unsigned p23 = pkbf(hv[2], hv[3]);                                 \
    const unsigned short hb16_0 = (unsigned short)p01;                       \
    const unsigned short hb16_1 = (unsigned short)(p01 >> 16);               \
    const unsigned short hb16_2 = (unsigned short)p23;                       \
    const unsigned short hb16_3 = (unsigned short)(p23 >> 16);               \
    hw[0] = hb16_0;                                                          \
    hw[8] = hb16_1;                                                          \
    hw[16] = hb16_2;                                                         \
    hw[24] = hb16_3;                                                         \
    if (((tpck >> 0) & 255u) == (unsigned)(T)) xtsbg[pbase + 0] = hb16_0;    \
    if (((tpck >> 8) & 255u) == (unsigned)(T)) xtsbg[pbase + 8] = hb16_1;    \
    if (((tpck >> 16) & 255u) == (unsigned)(T)) xtsbg[pbase + 16] = hb16_2;  \
    if (((tpck >> 24) & 255u) == (unsigned)(T)) xtsbg[pbase + 24] = hb16_3;  \
  }

__global__ __launch_bounds__(BLOCK) void recdqn_kernel(
    const float* __restrict__ s, const float* __restrict__ W_os,
    const float* __restrict__ b_os, const float* __restrict__ W_ih,
    const float* __restrict__ W_hh, const float* __restrict__ b_ih,
    const float* __restrict__ b_hh, const float* __restrict__ W_ts,
    const float* __restrict__ b_ts, const float* __restrict__ W_c1,
    const float* __restrict__ b_c1, const float* __restrict__ W_c2,
    const float* __restrict__ b_c2, const int* __restrict__ ws,
    float* __restrict__ out) {
  __shared__ unsigned short x_st[2][ROWS * 264]; // [chain][row][t][8] bf16
  __shared__ unsigned short hA[2][2][2048];      // [chain][buf] h A-frag
  __shared__ unsigned short xtsb[2][2048];       // captured h at t=len-1
  __shared__ unsigned short wihf[4 * 128 * 8];   // W_ih frags, ch6 = bias
  __shared__ unsigned short whh2[32768];         // W_hh kt=2,3 frags (64 KB);
                                                 // heads alias: xcat/x2b
  __shared__ int n_lds[2][ROWS];
  __shared__ int rid_s[2][ROWS];
  __shared__ int tmax_sh[2];

  const int tid = threadIdx.x;
  const int L = tid & 63;
  const int w = tid >> 6;   // wave 0..15
  const int g = w >> 3;     // group = chain 0..1
  const int ww = w & 7;     // wave within group: hidden cols [16ww,16ww+16)
  const int c = L & 15;
  const int q = L >> 4;
  const int j = (ww << 4) | c;
  const int qsw = (q ^ ((j >> 1) & 3)) << 3;  // swizzled whh2 q-slot (shorts)

  const short8 z8 = {0, 0, 0, 0, 0, 0, 0, 0};
  const f32x4 z4 = {0.0f, 0.0f, 0.0f, 0.0f};

  // ---- one-time: prescaled W_hh kt=0,1 B-fragments (regs)
  short8 Bh[4][2];
#pragma unroll
  for (int a = 0; a < 4; ++a) {
    const float sc = (a == 2) ? -2.88539008f : -1.44269504f;
    const int n = (a << 7) + j;
#pragma unroll
    for (int kt = 0; kt < 2; ++kt)
      Bh[a][kt] = pack8s(W_hh + n * HID + kt * 32 + q * 8, sc);
  }

  const int pbase = ((j >> 5) << 9) + (((j >> 3) & 3) << 7) + (q << 5) + (j & 7);

  // ---- pick tile pair: adjacent sorted tiles, longest-first (LPT)
  const int p = (PAIRS - 1) - blockIdx.x;
  if (tid < 32) {
    const int cn = tid >> 4, rr = tid & 15;
    const int row = ws[PERM_OFF + (2 * p + cn) * ROWS + rr];
    rid_s[cn][rr] = row;
    n_lds[cn][rr] = ws[LEN_OFF + row];
  }
  // ---- wihf staging (W_ih prescaled + bias in channel 6) + xtsb zero
  if (tid < 512) {
    const int a = tid >> 7, jj = tid & 127, n = (a << 7) + jj;
    const float sc = (a == 2) ? -2.88539008f : -1.44269504f;
    const float* px = W_ih + n * NOBS_TS;
    union { unsigned u[4]; short8 s; } fu;
    fu.u[0] = pkbf(px[0] * sc, px[1] * sc);
    fu.u[1] = pkbf(px[2] * sc, px[3] * sc);
    fu.u[2] = pkbf(px[4] * sc, px[5] * sc);
    fu.u[3] = pkbf(sc * (b_ih[n] + b_hh[n]), 0.0f);
    *(short8*)&wihf[tid * 8] = fu.s;
    *(short8*)&((unsigned short*)xtsb)[tid * 8] = z8;
  }
  // ---- whh2 staging: W_hh kt=2,3 prescaled bf16 B-frags, q-slot swizzled
  {
    const int gs = tid >> 7, jj = tid & 127;     // gs = a*2 + kth
    const int a = gs >> 1, kth = gs & 1;
    const float sc = (a == 2) ? -2.88539008f : -1.44269504f;
    const float* pw = W_hh + (a * 128 + jj) * HID + (2 + kth) * 32;
    unsigned short* dst = &whh2[(gs * 128 + jj) * 32];
    const int sw = (jj >> 1) & 3;
#pragma unroll
    for (int h = 0; h < 4; ++h)
      *(short8*)&dst[(h ^ sw) * 8] = pack8s(pw + h * 8, sc);
  }
  __syncthreads();

  // ---- stage s_TS -> LDS bf16 for both chains (ch6 = 1.0 inside length)
  {
    const int cn = tid >> 9, rt = tid & 511, r = rt >> 5, tq = rt & 31;
    short8 v = z8;
    if (tq < n_lds[cn][r]) {
      const float2* ps =
          (const float2*)(s + (size_t)rid_s[cn][r] * 200 + NOBS_OS + tq * NOBS_TS);
      const float2 A = ps[0], Bv = ps[1], Cv = ps[2];
      union { unsigned u[4]; short8 s; } vu;
      vu.u[0] = pkbf(A.x, A.y);
      vu.u[1] = pkbf(Bv.x, Bv.y);
      vu.u[2] = pkbf(Cv.x, Cv.y);
      vu.u[3] = pkbf(1.0f, 0.0f);   // bias channel
      v = vu.s;
    }
    *(short8*)&x_st[cn][r * 264 + tq * 8] = v;
  }
  if (tid == 0) {
#pragma unroll
    for (int cn = 0; cn < 2; ++cn) {
      int mx = 0;
      for (int r = 0; r < ROWS; ++r) mx = max(mx, n_lds[cn][r]);
      tmax_sh[cn] = mx;
    }
  }
  __syncthreads();

  const int tm1 = tmax_sh[1];           // chains sorted ascending: tm0 <= tm1
  const int tmg = tmax_sh[g];           // my group's trip count
  unsigned tpck = 0;
#pragma unroll
  for (int b = 0; b < 4; ++b)
    tpck |= ((unsigned)((n_lds[g][q * 4 + b] - 1) & 255)) << (b * 8);

  float cc[4] = {0.0f, 0.0f, 0.0f, 0.0f};
  const unsigned short* xstg = &x_st[g][0];
  unsigned short* hAg = &hA[g][0][0];
  unsigned short* xtsbg = &xtsb[g][0];

  // ---- LSTM time loop: group-predicated work, block-wide barriers
  f32x4 acc[4];
  if (tm1 > 0) {
    if (tmg > 0) { GX(0) ACT(0) }
    __syncthreads();
    for (int t = 1; t < tm1; ++t) {
      if (t < tmg) { GX(t) GH(t) ACT(t) }
      __syncthreads();
    }
  }
  // All whh2 reads are done (before the loop's final barrier); heads may
  // now alias whh2 as xcat/x2b scratch.
  unsigned short* xcatg = &whh2[g * 4096];        // concat A-frag (K=256)
  unsigned short* x2bg = &whh2[8192 + g * 2048];  // W_c1 out A-frag

  // ---- heads: each group processes its own chain; load-pack-use weights
  // x_TS = relu(xts @ W_ts^T + b_ts) -> xcat k=128+j
  {
    const float bts = b_ts[j];
    f32x4 a2 = {bts, bts, bts, bts};
#pragma unroll
    for (int kt = 0; kt < 4; ++kt) {
      const f32x4* pp = (const f32x4*)(W_ts + j * HID + kt * 32 + q * 8);
      const short8 fw = pack8(pp[0], pp[1]);
      const short8 af = *(const short8*)&xtsbg[kt * 512 + L * 8];
      a2 = __builtin_amdgcn_mfma_f32_16x16x32_bf16(af, fw, a2, 0, 0, 0);
    }
    const unsigned p01 = pkbf(fmaxf(a2[0], 0.0f), fmaxf(a2[1], 0.0f));
    const unsigned p23 = pkbf(fmaxf(a2[2], 0.0f), fmaxf(a2[3], 0.0f));
    xcatg[2048 + pbase + 0] = (unsigned short)p01;
    xcatg[2048 + pbase + 8] = (unsigned short)(p01 >> 16);
    xcatg[2048 + pbase + 16] = (unsigned short)p23;
    xcatg[2048 + pbase + 24] = (unsigned short)(p23 >> 16);
  }
  // x_OS = relu(s_OS @ W_os^T + b_os) -> xcat k=j
  {
    short8 aos = z8;
    if (q == 0) {
      const f32x4* pa = (const f32x4*)(s + (size_t)rid_s[g][c] * 200);
      aos = pack8(pa[0], pa[1]);
    }
    const f32x4* pb = (const f32x4*)(W_os + j * NOBS_OS);
    const short8 bosf = pack8(pb[0], pb[1]);
    const float bos = b_os[j];
    f32x4 a2 = {bos, bos, bos, bos};
    a2 = __builtin_amdgcn_mfma_f32_16x16x32_bf16(aos, bosf, a2, 0, 0, 0);
    const unsigned p01 = pkbf(fmaxf(a2[0], 0.0f), fmaxf(a2[1], 0.0f));
    const unsigned p23 = pkbf(fmaxf(a2[2], 0.0f), fmaxf(a2[3], 0.0f));
    xcatg[pbase + 0] = (unsigned short)p01;
    xcatg[pbase + 8] = (unsigned short)(p01 >> 16);
    xcatg[pbase + 16] = (unsigned short)p23;
    xcatg[pbase + 24] = (unsigned short)(p23 >> 16);
  }
  __syncthreads();
  // x = relu(xcat @ W_c1^T + b_c1) -> x2b (K=256)
  {
    const float bc1 = b_c1[j];
    f32x4 a2 = {bc1, bc1, bc1, bc1};
#pragma unroll
    for (int kt = 0; kt < 8; ++kt) {
      const f32x4* pp = (const f32x4*)(W_c1 + j * 256 + kt * 32 + q * 8);
      const short8 fw = pack8(pp[0], pp[1]);
      const short8 af = *(const short8*)&xcatg[kt * 512 + L * 8];
      a2 = __builtin_amdgcn_mfma_f32_16x16x32_bf16(af, fw, a2, 0, 0, 0);
    }
    const unsigned p01 = pkbf(fmaxf(a2[0], 0.0f), fmaxf(a2[1], 0.0f));
    const unsigned p23 = pkbf(fmaxf(a2[2], 0.0f), fmaxf(a2[3], 0.0f));
    x2bg[pbase + 0] = (unsigned short)p01;
    x2bg[pbase + 8] = (unsigned short)(p01 >> 16);
    x2bg[pbase + 16] = (unsigned short)p23;
    x2bg[pbase + 24] = (unsigned short)(p23 >> 16);
  }
  __syncthreads();
  // out = x2 @ W_c2^T + b_c2 (wave ww==0 of each group; cols c<9 valid)
  if (ww == 0) {
    const float bc2 = (c < NACT) ? b_c2[c] : 0.0f;
    f32x4 accf = {bc2, bc2, bc2, bc2};
#pragma unroll
    for (int kt = 0; kt < 4; ++kt) {
      short8 fw = z8;
      if (c < NACT) {
        const f32x4* pp = (const f32x4*)(W_c2 + c * HID + kt * 32 + q * 8);
        fw = pack8(pp[0], pp[1]);
      }
      const short8 af = *(const short8*)&x2bg[kt * 512 + L * 8];
      accf = __builtin_amdgcn_mfma_f32_16x16x32_bf16(af, fw, accf, 0, 0, 0);
    }
    if (c < NACT) {
#pragma unroll
      for (int r = 0; r < 4; ++r)
        out[(size_t)rid_s[g][q * 4 + r] * NACT + c] = accf[r];
    }
  }
}

extern "C" void kernel_launch(void* const* d_in, const int* in_sizes, int n_in,
                              void* d_out, int out_size, void* d_ws, size_t ws_size,
                              hipStream_t stream) {
  (void)in_sizes; (void)n_in; (void)out_size; (void)ws_size;
  const float* s    = (const float*)d_in[0];
  const float* W_os = (const float*)d_in[1];
  const float* b_os = (const float*)d_in[2];
  const float* W_ih = (const float*)d_in[3];
  const float* W_hh = (const float*)d_in[4];
  const float* b_ih = (const float*)d_in[5];
  const float* b_hh = (const float*)d_in[6];
  const float* W_ts = (const float*)d_in[7];
  const float* b_ts = (const float*)d_in[8];
  const float* W_c1 = (const float*)d_in[9];
  const float* b_c1 = (const float*)d_in[10];
  const float* W_c2 = (const float*)d_in[11];
  const float* b_c2 = (const float*)d_in[12];
  int* ws = (int*)d_ws;
  float* outp = (float*)d_out;

  count_kernel<<<PREB, 256, 0, stream>>>(s, ws);
  scatter_kernel<<<PREB, 256, 0, stream>>>(ws);
  recdqn_kernel<<<PAIRS, BLOCK, 0, stream>>>(
      s, W_os, b_os, W_ih, W_hh, b_ih, b_hh, W_ts, b_ts, W_c1, b_c1, W_c2,
      b_c2, ws, outp);
}

// Round 6
// 251.533 us; speedup vs baseline: 1.4819x; 1.2300x over previous
//
#include <hip/hip_runtime.h>

#ifndef __has_builtin
#define __has_builtin(x) 0
#endif

#define NOBS_OS 8
#define NOBS_TS 6
#define HID 128
#define NACT 9
#define BTOT 32768
#define NTS 32
#define ROWS 16        // batch rows per tile
#define NTILES 2048    // 2048*16 = 32768
#define QUADS 512      // total quads of adjacent sorted tiles
#define GRID 256       // one block per CU; each does quads {511-bid, bid}
#define BLOCK 512      // 8 waves; wave w owns hidden cols [16w,16w+16)
#define PREB 128       // pre-pass blocks (256 thr each)

// workspace layout (int32 offsets)
#define LEN_OFF 0
#define PERM_OFF BTOT
#define HIST_OFF (2 * BTOT)   // PREB x 33 per-block histograms

typedef __attribute__((ext_vector_type(8))) short short8;
typedef __attribute__((ext_vector_type(4))) float f32x4;

__device__ inline unsigned short f2bf(float x) {
  unsigned int u = __float_as_uint(x);
  u += 0x7FFFu + ((u >> 16) & 1u);
  return (unsigned short)(u >> 16);
}

// packed f32x2 -> bf16x2 (low = a, high = b)
__device__ inline unsigned pkbf(float a, float b) {
#if __has_builtin(__builtin_amdgcn_cvt_pk_bf16_f32)
  auto v = __builtin_amdgcn_cvt_pk_bf16_f32(a, b);
  unsigned u;
  __builtin_memcpy(&u, &v, sizeof(u));
  return u;
#else
  return ((unsigned)f2bf(b) << 16) | (unsigned)f2bf(a);
#endif
}

__device__ inline float fexp2(float x) {
#if __has_builtin(__builtin_amdgcn_exp2f)
  return __builtin_amdgcn_exp2f(x);
#else
  return exp2f(x);
#endif
}
__device__ inline float frcp_(float x) {
#if __has_builtin(__builtin_amdgcn_rcpf)
  return __builtin_amdgcn_rcpf(x);
#else
  return 1.0f / x;
#endif
}

__device__ inline short8 pack8(f32x4 a, f32x4 b) {
  union { unsigned u[4]; short8 s; } r;
  r.u[0] = pkbf(a[0], a[1]); r.u[1] = pkbf(a[2], a[3]);
  r.u[2] = pkbf(b[0], b[1]); r.u[3] = pkbf(b[2], b[3]);
  return r.s;
}

__device__ inline short8 pack8s(const float* p, float s) {
  union { unsigned u[4]; short8 r; } r;
#pragma unroll
  for (int i = 0; i < 4; ++i) r.u[i] = pkbf(p[2 * i] * s, p[2 * i + 1] * s);
  return r.r;
}

// ---- fused counting-sort pre-pass (2 kernels, no global atomics) --------
__global__ void count_kernel(const float* __restrict__ s, int* __restrict__ ws) {
  __shared__ int lh[NTS + 1];
  const int tid = threadIdx.x;
  if (tid <= NTS) lh[tid] = 0;
  __syncthreads();
  const int row = blockIdx.x * 256 + tid;
  const float* p = s + (size_t)row * 200 + NOBS_OS;
  int lo = 0, hi = NTS;
  while (lo < hi) {
    const int mid = (lo + hi) >> 1;
    const float v = p[mid * NOBS_TS];
    if (v == v) lo = mid + 1; else hi = mid;
  }
  ws[LEN_OFF + row] = lo;
  atomicAdd(&lh[lo], 1);
  __syncthreads();
  if (tid <= NTS) ws[HIST_OFF + blockIdx.x * (NTS + 1) + tid] = lh[tid];
}

__global__ void scatter_kernel(int* __restrict__ ws) {
  __shared__ int tot[NTS + 1], pre[NTS + 1], gb[NTS + 1], lh[NTS + 1];
  const int tid = threadIdx.x;
  if (tid <= NTS) {
    int t = 0, pr = 0;
    for (int k = 0; k < PREB; ++k) {
      const int h = ws[HIST_OFF + k * (NTS + 1) + tid];
      t += h;
      if (k < (int)blockIdx.x) pr += h;
    }
    tot[tid] = t;
    pre[tid] = pr;
    lh[tid] = 0;
  }
  __syncthreads();
  if (tid == 0) {
    int a = 0;
    for (int b = 0; b <= NTS; ++b) { gb[b] = a; a += tot[b]; }
  }
  __syncthreads();
  const int row = blockIdx.x * 256 + tid;
  const int len = ws[LEN_OFF + row];
  const int r = atomicAdd(&lh[len], 1);
  __syncthreads();
  ws[PERM_OFF + gb[len] + pre[len] + r] = row;
}

// ---- main fused kernel: quad-chain, PHASE-BATCHED steps ------------------
// Round-0 structure (proven best: fat barrier-steps, 4-chain ILP per wave,
// all W_hh in regs). Rounds 1-5 established: raising waves/SIMD forces
// 1-chain waves (W_hh needs 64 VGPRs/wave) -> thinner steps -> slower.
// THIS round's change: load balance. 512 blocks on 256 CUs with reversed
// LPT gave worst-CU ~48 steps vs 33 avg. Now GRID=256 (1 block/CU, all
// co-resident by construction -- no dispatch-order assumption), each block
// processes complementary quads {511-bid, bid}; per-block step total
// ~ const ~ 33-34 since quad tmax is ~linear in sorted index. Weight
// prologue per block amortized over both quads.
// A-frag layout in LDS (16 rows x K): elem idx = kt*512 + lane*8 + jj
// C-layout writes at column k: idx = (k>>5)*512 + ((k>>3)&3)*128 + m*8 + (k&7)
// Weights prescaled: i,f,o by -1/log2(e), g by -2/log2(e); fused products:
//   i*g = (1-eg)*rcp((1+ei)(1+eg)); f*c = c*rcp(1+ef);
//   o*tanh(c) = (1-ec)*rcp((1+eo)(1+ec)), ec = exp2(-2c*log2e)
// Per quad-step: ALL chains' MFMAs issue first (acc[4][4] live -> cross-chain
// overlap), then ALL chains' activations. Bias rides as the MFMA C operand.
// x_TS capture is register-based. Chain index CN must be a literal.

#define GX(CN, T)                                                            \
  {                                                                          \
    short8 ax = z8;                                                          \
    if (q == 0) ax = *(const short8*)&x_st[CN][c * 264 + (T) * 8];           \
    _Pragma("unroll") for (int a = 0; a < 4; ++a)                            \
        acc[CN][a] = __builtin_amdgcn_mfma_f32_16x16x32_bf16(                \
            ax, Bh[a][4], biasv[a], 0, 0, 0);                                \
  }

#define GH(CN, T)                                                            \
  {                                                                          \
    const unsigned short* hb = hA[CN][((T) + 1) & 1];                        \
    _Pragma("unroll") for (int kt = 0; kt < 4; ++kt) {                       \
      const short8 ah = *(const short8*)&hb[kt * 512 + L * 8];               \
      _Pragma("unroll") for (int a = 0; a < 4; ++a)                          \
          acc[CN][a] = __builtin_amdgcn_mfma_f32_16x16x32_bf16(              \
              ah, Bh[a][kt], acc[CN][a], 0, 0, 0);                           \
    }                                                                        \
  }

#define ACT(CN, T)                                                           \
  {                                                                          \
    unsigned short* hw = &hA[CN][(T) & 1][pbase];                            \
    float hv[4];                                                             \
    _Pragma("unroll") for (int r = 0; r < 4; ++r) {                          \
      const float ei = fexp2(acc[CN][0][r]);                                 \
      const float ef = fexp2(acc[CN][1][r]);                                 \
      const float eg = fexp2(acc[CN][2][r]);                                 \
      const float eo = fexp2(acc[CN][3][r]);                                 \
      const float rig = frcp_((1.0f + ei) * (1.0f + eg));                    \
      const float rf = frcp_(1.0f + ef);                                     \
      const float cv = cc[CN][r] * rf + (1.0f - eg) * rig;                   \
      cc[CN][r] = cv;                                                        \
      const float ec = fexp2(cv * -2.88539008f);                             \
      const float roc = frcp_((1.0f + eo) * (1.0f + ec));                    \
      hv[r] = (1.0f - ec) * roc;                                             \
    }                                                                        \
    const unsigned p01 = pkbf(hv[0], hv[1]);                                 \
    const unsigned p23 = pkbf(hv[2], hv[3]);                                 \
    hw[0] = (unsigned short)p01;                                             \
    hw[8] = (unsigned short)(p01 >> 16);                                     \
    hw[16] = (unsigned short)p23;                                            \
    hw[24] = (unsigned short)(p23 >> 16);                                    \
    _Pragma("unroll") for (int r = 0; r < 4; ++r) {                          \
      if (((tpck[CN] >> (r * 8)) & 255u) == (unsigned)(T))                   \
        xts[CN][r] = hv[r];                                                  \
    }                                                                        \
  }

__global__ __launch_bounds__(BLOCK, 2) void recdqn_kernel(
    const float* __restrict__ s, const float* __restrict__ W_os,
    const float* __restrict__ b_os, const float* __restrict__ W_ih,
    const float* __restrict__ W_hh, const float* __restrict__ b_ih,
    const float* __restrict__ b_hh, const float* __restrict__ W_ts,
    const float* __restrict__ b_ts, const float* __restrict__ W_c1,
    const float* __restrict__ b_c1, const float* __restrict__ W_c2,
    const float* __restrict__ b_c2, const int* __restrict__ ws,
    float* __restrict__ out) {
  __shared__ unsigned short x_st[4][ROWS * 264]; // [chain][row][t][8] bf16
  __shared__ unsigned short hA[4][2][2048];      // [chain][buf] h A-frag
  __shared__ unsigned short xtsb[4][2048];       // captured h at t=len-1
  __shared__ unsigned short xcat[4096];          // concat A-frag (K=256), shared
  __shared__ unsigned short x2b[2048];           // W_c1 out A-frag, shared
  __shared__ int n_lds[4][ROWS];
  __shared__ int rid_s[4][ROWS];
  __shared__ int tmax_sh[4];

  const int tid = threadIdx.x;
  const int L = tid & 63;
  const int w = tid >> 6;   // wave 0..7: hidden cols [16w, 16w+16)
  const int c = L & 15;
  const int q = L >> 4;
  const int j = (w << 4) | c;

  const short8 z8 = {0, 0, 0, 0, 0, 0, 0, 0};

  // ---- one-time: prescaled W_hh/W_ih B-fragments + bias vectors
  short8 Bh[4][5];
  f32x4 biasv[4];
#pragma unroll
  for (int a = 0; a < 4; ++a) {
    const float sc = (a == 2) ? -2.88539008f : -1.44269504f;
    const int n = (a << 7) + j;
    const float bb = sc * (b_ih[n] + b_hh[n]);
    f32x4 bv = {bb, bb, bb, bb};
    biasv[a] = bv;
#pragma unroll
    for (int kt = 0; kt < 4; ++kt)
      Bh[a][kt] = pack8s(W_hh + n * HID + kt * 32 + q * 8, sc);
    short8 fx = z8;
    if (q == 0) {
      const float* px = W_ih + n * NOBS_TS;
      union { unsigned u[4]; short8 s; } fu;
      fu.u[0] = pkbf(px[0] * sc, px[1] * sc);
      fu.u[1] = pkbf(px[2] * sc, px[3] * sc);
      fu.u[2] = pkbf(px[4] * sc, px[5] * sc);
      fu.u[3] = 0;
      fx = fu.s;
    }
    Bh[a][4] = fx;
  }

  const int pbase = ((j >> 5) << 9) + (((j >> 3) & 3) << 7) + (q << 5) + (j & 7);

  // ---- two complementary quads per block: {511-bid, bid}
#pragma unroll 1
  for (int seg = 0; seg < 2; ++seg) {
    const int p = seg == 0 ? (QUADS - 1 - (int)blockIdx.x) : (int)blockIdx.x;

    if (tid < 64) {
      const int cn = tid >> 4, rr = tid & 15;
      const int row = ws[PERM_OFF + (4 * p + cn) * ROWS + rr];
      rid_s[cn][rr] = row;
      n_lds[cn][rr] = ws[LEN_OFF + row];
    }
    __syncthreads();

    // ---- stage s_TS -> LDS bf16 for all 4 chains (zeros past length)
#pragma unroll
    for (int it = 0; it < 4; ++it) {
      const int slot = tid + it * 512;
      const int cn = slot >> 9, rt = slot & 511, r = rt >> 5, tq = rt & 31;
      short8 v = z8;
      if (tq < n_lds[cn][r]) {
        const float2* ps =
            (const float2*)(s + (size_t)rid_s[cn][r] * 200 + NOBS_OS + tq * NOBS_TS);
        const float2 A = ps[0], Bv = ps[1], Cv = ps[2];
        union { unsigned u[4]; short8 s; } vu;
        vu.u[0] = pkbf(A.x, A.y);
        vu.u[1] = pkbf(Bv.x, Bv.y);
        vu.u[2] = pkbf(Cv.x, Cv.y);
        vu.u[3] = 0;
        v = vu.s;
      }
      *(short8*)&x_st[cn][r * 264 + tq * 8] = v;
    }
    if (tid == 0) {
#pragma unroll
      for (int cn = 0; cn < 4; ++cn) {
        int mx = 0;
        for (int r = 0; r < ROWS; ++r) mx = max(mx, n_lds[cn][r]);
        tmax_sh[cn] = mx;
      }
    }
    __syncthreads();

    const int tm0 = tmax_sh[0], tm1 = tmax_sh[1];
    const int tm2 = tmax_sh[2], tm3 = tmax_sh[3]; // ascending (sorted)
    unsigned tpck[4];
#pragma unroll
    for (int cn = 0; cn < 4; ++cn) {
      unsigned pk = 0;
#pragma unroll
      for (int b = 0; b < 4; ++b)
        pk |= ((unsigned)((n_lds[cn][q * 4 + b] - 1) & 255)) << (b * 8);
      tpck[cn] = pk;
    }

    float cc[4][4], xts[4][4];
#pragma unroll
    for (int i = 0; i < 4; ++i) {
      cc[0][i] = 0.0f; cc[1][i] = 0.0f; cc[2][i] = 0.0f; cc[3][i] = 0.0f;
      xts[0][i] = 0.0f; xts[1][i] = 0.0f; xts[2][i] = 0.0f; xts[3][i] = 0.0f;
    }

    // ---- quad-chain LSTM time loop, phase-batched
    f32x4 acc[4][4];
    if (tm3 > 0) {
      if (tm0 > 0) GX(0, 0)
      if (tm1 > 0) GX(1, 0)
      if (tm2 > 0) GX(2, 0)
      GX(3, 0)
      if (tm0 > 0) ACT(0, 0)
      if (tm1 > 0) ACT(1, 0)
      if (tm2 > 0) ACT(2, 0)
      ACT(3, 0)
      __syncthreads();
      int t = 1;
      for (; t < tm0; ++t) {
        GX(0, t) GH(0, t)
        GX(1, t) GH(1, t)
        GX(2, t) GH(2, t)
        GX(3, t) GH(3, t)
        ACT(0, t) ACT(1, t) ACT(2, t) ACT(3, t)
        __syncthreads();
      }
      for (; t < tm1; ++t) {
        GX(1, t) GH(1, t)
        GX(2, t) GH(2, t)
        GX(3, t) GH(3, t)
        ACT(1, t) ACT(2, t) ACT(3, t)
        __syncthreads();
      }
      for (; t < tm2; ++t) {
        GX(2, t) GH(2, t)
        GX(3, t) GH(3, t)
        ACT(2, t) ACT(3, t)
        __syncthreads();
      }
      for (; t < tm3; ++t) {
        GX(3, t) GH(3, t)
        ACT(3, t)
        __syncthreads();
      }
    }

    // ---- write captured x_TS (registers) -> xtsb in A-frag layout
#pragma unroll
    for (int cn = 0; cn < 4; ++cn) {
      const unsigned p01 = pkbf(xts[cn][0], xts[cn][1]);
      const unsigned p23 = pkbf(xts[cn][2], xts[cn][3]);
      unsigned short* pw = &xtsb[cn][pbase];
      pw[0] = (unsigned short)p01;
      pw[8] = (unsigned short)(p01 >> 16);
      pw[16] = (unsigned short)p23;
      pw[24] = (unsigned short)(p23 >> 16);
    }
    __syncthreads();

    // ---- hoisted head weight fragments (bf16), reused by all chains
    short8 Fts[4], Fc1[8], Fc2[4], bosf = z8;
#pragma unroll
    for (int kt = 0; kt < 4; ++kt) {
      const f32x4* pp = (const f32x4*)(W_ts + j * HID + kt * 32 + q * 8);
      Fts[kt] = pack8(pp[0], pp[1]);
    }
#pragma unroll
    for (int kt = 0; kt < 8; ++kt) {
      const f32x4* pp = (const f32x4*)(W_c1 + j * 256 + kt * 32 + q * 8);
      Fc1[kt] = pack8(pp[0], pp[1]);
    }
#pragma unroll
    for (int kt = 0; kt < 4; ++kt) Fc2[kt] = z8;
    if (w == 0 && c < NACT) {
#pragma unroll
      for (int kt = 0; kt < 4; ++kt) {
        const f32x4* pp = (const f32x4*)(W_c2 + c * HID + kt * 32 + q * 8);
        Fc2[kt] = pack8(pp[0], pp[1]);
      }
    }
    if (q == 0) {
      const f32x4* pb = (const f32x4*)(W_os + j * NOBS_OS);
      bosf = pack8(pb[0], pb[1]);
    }
    const float bts = b_ts[j], bc1 = b_c1[j], bos = b_os[j];
    const float bc2 = (w == 0 && c < NACT) ? b_c2[c] : 0.0f;

    // ---- heads, per chain (shared xcat/x2b)
#pragma unroll 1
    for (int cn = 0; cn < 4; ++cn) {
      // x_TS = relu(xts @ W_ts^T + b_ts) -> xcat k=128+j
      {
        f32x4 a2 = {bts, bts, bts, bts};
#pragma unroll
        for (int kt = 0; kt < 4; ++kt) {
          const short8 af = *(const short8*)&xtsb[cn][kt * 512 + L * 8];
          a2 = __builtin_amdgcn_mfma_f32_16x16x32_bf16(af, Fts[kt], a2, 0, 0, 0);
        }
        const unsigned p01 = pkbf(fmaxf(a2[0], 0.0f), fmaxf(a2[1], 0.0f));
        const unsigned p23 = pkbf(fmaxf(a2[2], 0.0f), fmaxf(a2[3], 0.0f));
        xcat[2048 + pbase + 0] = (unsigned short)p01;
        xcat[2048 + pbase + 8] = (unsigned short)(p01 >> 16);
        xcat[2048 + pbase + 16] = (unsigned short)p23;
        xcat[2048 + pbase + 24] = (unsigned short)(p23 >> 16);
      }
      // x_OS = relu(s_OS @ W_os^T + b_os) -> xcat k=j
      {
        short8 aos = z8;
        if (q == 0) {
          const f32x4* pa = (const f32x4*)(s + (size_t)rid_s[cn][c] * 200);
          aos = pack8(pa[0], pa[1]);
        }
        f32x4 a2 = {bos, bos, bos, bos};
        a2 = __builtin_amdgcn_mfma_f32_16x16x32_bf16(aos, bosf, a2, 0, 0, 0);
        const unsigned p01 = pkbf(fmaxf(a2[0], 0.0f), fmaxf(a2[1], 0.0f));
        const unsigned p23 = pkbf(fmaxf(a2[2], 0.0f), fmaxf(a2[3], 0.0f));
        xcat[pbase + 0] = (unsigned short)p01;
        xcat[pbase + 8] = (unsigned short)(p01 >> 16);
        xcat[pbase + 16] = (unsigned short)p23;
        xcat[pbase + 24] = (unsigned short)(p23 >> 16);
      }
      __syncthreads();
      // x = relu(xcat @ W_c1^T + b_c1) -> x2b (K=256)
      {
        f32x4 a2 = {bc1, bc1, bc1, bc1};
#pragma unroll
        for (int kt = 0; kt < 8; ++kt) {
          const short8 af = *(const short8*)&xcat[kt * 512 + L * 8];
          a2 = __builtin_amdgcn_mfma_f32_16x16x32_bf16(af, Fc1[kt], a2, 0, 0, 0);
        }
        const unsigned p01 = pkbf(fmaxf(a2[0], 0.0f), fmaxf(a2[1], 0.0f));
        const unsigned p23 = pkbf(fmaxf(a2[2], 0.0f), fmaxf(a2[3], 0.0f));
        x2b[pbase + 0] = (unsigned short)p01;
        x2b[pbase + 8] = (unsigned short)(p01 >> 16);
        x2b[pbase + 16] = (unsigned short)p23;
        x2b[pbase + 24] = (unsigned short)(p23 >> 16);
      }
      __syncthreads();
      // out = x2 @ W_c2^T + b_c2 (wave 0; cols c<9 valid)
      if (w == 0) {
        f32x4 accf = {bc2, bc2, bc2, bc2};
#pragma unroll
        for (int kt = 0; kt < 4; ++kt) {
          const short8 af = *(const short8*)&x2b[kt * 512 + L * 8];
          accf = __builtin_amdgcn_mfma_f32_16x16x32_bf16(af, Fc2[kt], accf, 0, 0, 0);
        }
        if (c < NACT) {
#pragma unroll
          for (int r = 0; r < 4; ++r)
            out[(size_t)rid_s[cn][q * 4 + r] * NACT + c] = accf[r];
        }
      }
      __syncthreads(); // protect xcat/x2b reuse by next chain / next seg
    }
  }
}

extern "C" void kernel_launch(void* const* d_in, const int* in_sizes, int n_in,
                              void* d_out, int out_size, void* d_ws, size_t ws_size,
                              hipStream_t stream) {
  (void)in_sizes; (void)n_in; (void)out_size; (void)ws_size;
  const float* s    = (const float*)d_in[0];
  const float* W_os = (const float*)d_in[1];
  const float* b_os = (const float*)d_in[2];
  const float* W_ih = (const float*)d_in[3];
  const float* W_hh = (const float*)d_in[4];
  const float* b_ih = (const float*)d_in[5];
  const float* b_hh = (const float*)d_in[6];
  const float* W_ts = (const float*)d_in[7];
  const float* b_ts = (const float*)d_in[8];
  const float* W_c1 = (const float*)d_in[9];
  const float* b_c1 = (const float*)d_in[10];
  const float* W_c2 = (const float*)d_in[11];
  const float* b_c2 = (const float*)d_in[12];
  int* ws = (int*)d_ws;
  float* outp = (float*)d_out;

  count_kernel<<<PREB, 256, 0, stream>>>(s, ws);
  scatter_kernel<<<PREB, 256, 0, stream>>>(ws);
  recdqn_kernel<<<GRID, BLOCK, 0, stream>>>(
      s, W_os, b_os, W_ih, W_hh, b_ih, b_hh, W_ts, b_ts, W_c1, b_c1, W_c2,
      b_c2, ws, outp);
}